// Round 1
// 289.674 us; speedup vs baseline: 1.0060x; 1.0060x over previous
//
#include <hip/hip_runtime.h>
#include <math.h>

// Mean over B rows of KL divergence between diagonal Gaussians.
// B=65536, N=256. out = 0.5 * (sum_all(term)/B - N), where
// term = log(s2)-log(s1) + s1/s2 + (mask*(mu2-mu1))^2/s2.
//
// R6 experiment: decorrelate the 5 input streams.
//  - Arrays are exactly 64 MiB apart -> phase-aligned over any pow2
//    channel/bank interleave. All blocks also read arrays in the SAME
//    order simultaneously. Rotate per-block array order (blockIdx%5)
//    to break the machine-wide phase sync.
//  - sched_barrier(0) after the load cluster forces all 20 float4
//    loads in flight per wave (prior compile batched them, VGPR=36).
// If this is neutral (+-3%), the ~3.0 TB/s delivered-read plateau is
// source-independent and we accept the delivery-path roofline.

constexpr int B_ROWS = 65536;
constexpr int N_COLS = 256;
constexpr int TOTAL4 = (B_ROWS * N_COLS) / 4;  // 4,194,304 float4s per array
constexpr int GRID1  = 4096;
constexpr int BLOCK  = 256;
constexpr int ITERS  = TOTAL4 / (GRID1 * BLOCK);  // = 4 float4s/thread/array
static_assert(ITERS == 4, "load macro below hardcodes ITERS==4");

__device__ __forceinline__ float kl_term(float m1, float m2, float s1, float s2, float mk) {
    m1 = __builtin_isnan(m1) ? 0.0f : m1;      // nan_to_num(mu1)
    float d  = mk * (m2 - m1);
    float r2 = __builtin_amdgcn_rcpf(s2);      // tolerance is 2%; approx ok
    float lg = 0.69314718055994531f * (__log2f(s2) - __log2f(s1));
    return lg + (s1 + d * d) * r2;
}

__device__ __forceinline__ float kl4(float4 a, float4 b, float4 p, float4 q, float4 m) {
    return kl_term(a.x, b.x, p.x, q.x, m.x)
         + kl_term(a.y, b.y, p.y, q.y, m.y)
         + kl_term(a.z, b.z, p.z, q.z, m.z)
         + kl_term(a.w, b.w, p.w, q.w, m.w);
}

__global__ __launch_bounds__(BLOCK, 4) void kl_partial_kernel(
    const float4* __restrict__ mu1, const float4* __restrict__ mu2,
    const float4* __restrict__ s1,  const float4* __restrict__ s2,
    const float4* __restrict__ mask, float* __restrict__ partials)
{
    const int base = blockIdx.x * (BLOCK * ITERS) + threadIdx.x;

    float4 A[ITERS], Bv[ITERS], P[ITERS], Q[ITERS], M[ITERS];

    // 4 explicit loads per array (ITERS==4), issued in per-block-rotated
    // array order so neighbouring blocks stress different streams at any
    // given moment.
#define LD(dst, src)                      \
    dst[0] = src[base];                   \
    dst[1] = src[base + BLOCK];           \
    dst[2] = src[base + 2 * BLOCK];       \
    dst[3] = src[base + 3 * BLOCK];

    switch (blockIdx.x % 5u) {
    case 0u: LD(A, mu1) LD(Bv, mu2) LD(P, s1)  LD(Q, s2)  LD(M, mask) break;
    case 1u: LD(Bv, mu2) LD(P, s1)  LD(Q, s2)  LD(M, mask) LD(A, mu1) break;
    case 2u: LD(P, s1)  LD(Q, s2)  LD(M, mask) LD(A, mu1) LD(Bv, mu2) break;
    case 3u: LD(Q, s2)  LD(M, mask) LD(A, mu1) LD(Bv, mu2) LD(P, s1)  break;
    default: LD(M, mask) LD(A, mu1) LD(Bv, mu2) LD(P, s1)  LD(Q, s2)  break;
    }
#undef LD

    // Keep all 20 loads in flight: no compute may be hoisted above this
    // point, no load sunk below it.
    __builtin_amdgcn_sched_barrier(0);

    float acc0 = 0.0f, acc1 = 0.0f;
    #pragma unroll
    for (int k = 0; k < ITERS; k += 2) {
        acc0 += kl4(A[k],     Bv[k],     P[k],     Q[k],     M[k]);
        acc1 += kl4(A[k + 1], Bv[k + 1], P[k + 1], Q[k + 1], M[k + 1]);
    }
    float acc = acc0 + acc1;

    // wave-64 reduction
    #pragma unroll
    for (int off = 32; off > 0; off >>= 1) acc += __shfl_down(acc, off, 64);
    __shared__ float wsum[BLOCK / 64];
    const int lane = threadIdx.x & 63;
    const int wv   = threadIdx.x >> 6;
    if (lane == 0) wsum[wv] = acc;
    __syncthreads();
    if (threadIdx.x == 0) {
        float s = 0.0f;
        #pragma unroll
        for (int w = 0; w < BLOCK / 64; ++w) s += wsum[w];
        partials[blockIdx.x] = s;  // unconditional write every launch (poison-safe)
    }
}

__global__ __launch_bounds__(BLOCK) void kl_final_kernel(
    const float* __restrict__ partials, float* __restrict__ out)
{
    double acc = 0.0;
    for (int i = threadIdx.x; i < GRID1; i += BLOCK) acc += (double)partials[i];
    #pragma unroll
    for (int off = 32; off > 0; off >>= 1) acc += __shfl_down(acc, off, 64);
    __shared__ double wsum[BLOCK / 64];
    const int lane = threadIdx.x & 63;
    const int wv   = threadIdx.x >> 6;
    if (lane == 0) wsum[wv] = acc;
    __syncthreads();
    if (threadIdx.x == 0) {
        double s = 0.0;
        #pragma unroll
        for (int w = 0; w < BLOCK / 64; ++w) s += wsum[w];
        out[0] = (float)(0.5 * s / (double)B_ROWS - 0.5 * (double)N_COLS);
    }
}

extern "C" void kernel_launch(void* const* d_in, const int* in_sizes, int n_in,
                              void* d_out, int out_size, void* d_ws, size_t ws_size,
                              hipStream_t stream) {
    const float4* mu1  = (const float4*)d_in[0];
    const float4* mu2  = (const float4*)d_in[1];
    const float4* sg1  = (const float4*)d_in[2];
    const float4* sg2  = (const float4*)d_in[3];
    const float4* mask = (const float4*)d_in[4];
    float* partials = (float*)d_ws;  // GRID1 floats = 16 KiB scratch
    float* out = (float*)d_out;

    kl_partial_kernel<<<GRID1, BLOCK, 0, stream>>>(mu1, mu2, sg1, sg2, mask, partials);
    kl_final_kernel<<<1, BLOCK, 0, stream>>>(partials, out);
}